// Round 2
// 311.333 us; speedup vs baseline: 1.2812x; 1.2812x over previous
//
#include <hip/hip_runtime.h>
#include <math.h>

// RWKV-6 fully-fused chunked scan.  B=4 H=32 T=2048 K=V=64.
// One kernel: 256 blocks = (bh 0..127) x (v-half 0..1), 512 threads (8 waves),
// exactly 1 block/CU.  Each block walks its (b,h)'s 32 chunks of CL=64
// sequentially, holding the 64x32 fp32 state slice in registers (4/thread).
// Eliminates the 67MB S workspace round-trip and the k,v,w re-read of the
// old 3-phase pipeline (810 MB -> ~335 MB of HBM traffic per iteration).
//
// Numerics: identical anchoring to the verified 3-phase kernel.
//   Qh = q*e^{cw_{t-1}-Cmid}, Kh = k*e^{Cmid-cw_s}  (Cmid = cw_31, |exp|<=e^64)
//   Qt = q*e^{cw_{t-1}};  A-diag = q*u*k;  masked-region inf discarded.
//   S_c = (V . Kh^T) * e^{tot-Cmid} per-k;  h = h*e^{tot} + S_c.
//
// LDS layout choices (conflict-driven):
//   Vt/Ht stored TRANSPOSED ([v][s]/[v][k]) -> all o/S_c frags are contiguous
//   ds_read_b128 (the old strided-u16 8-way-conflict reads are gone).
//   Kh stored with 8-elem-block XOR swizzle (blk ^= (s>>3)&7): row reads stay
//   single b128 (swizzled block idx), column reads (S_c B-frag) spread banks
//   (8-way -> 4-way).

#define Bdim 4
#define Hdim 32
#define Tdim 2048
#define Kdim 64
#define Vdim 64
#define NC   32
#define CL   64
#define LP   72   // padded LDS row stride (bf16 elems): 144 B, 16B-aligned rows

typedef __attribute__((ext_vector_type(8))) short short8;
typedef __attribute__((ext_vector_type(4))) float float4_;

__device__ __forceinline__ short f2bf(float x) {
    unsigned u = __float_as_uint(x);
    unsigned r = (u + 0x7FFFu + ((u >> 16) & 1u)) >> 16;
    return (short)r;
}

#define MFMA(a, b, c) __builtin_amdgcn_mfma_f32_16x16x32_bf16(a, b, c, 0, 0, 0)

__global__ __launch_bounds__(512) void rwkv6_fused(
    const float* __restrict__ rin, const float* __restrict__ kin,
    const float* __restrict__ vin, const float* __restrict__ win,
    const float* __restrict__ uin, const float* __restrict__ init,
    float* __restrict__ oout, float* __restrict__ fin)
{
    __shared__ __attribute__((aligned(16))) short Qh[CL * LP];
    __shared__ __attribute__((aligned(16))) short Kh[CL * LP];   // XOR-swizzled blocks
    __shared__ __attribute__((aligned(16))) short Qt[CL * LP];
    __shared__ __attribute__((aligned(16))) short Am[CL * LP];
    __shared__ __attribute__((aligned(16))) short Vt[32 * LP];   // V^T[v_local][s]
    __shared__ __attribute__((aligned(16))) short Ht[32 * LP];   // h0^T[v_local][k] (bf16 copy)
    __shared__ float bsum[8 * 64];
    __shared__ float Dd[CL];

    const int tid  = threadIdx.x;
    const int wv   = tid >> 6;          // wave 0..7
    const int lane = tid & 63;          // k index in preprocessing
    const int quad = lane >> 4, r = lane & 15;

    const int bid = blockIdx.x;
    const int vh  = bid >> 7;           // v-half 0/1 (siblings share XCD: 128%8==0)
    const int bh  = bid & 127;
    const int h_idx = bh & (Hdim - 1);

    // state / S_c mapping: wave -> (v-tile m_s, k-tile n_s)
    const int m_s = wv >> 2;            // 0..1
    const int n_s = wv & 3;             // 0..3
    const int k_  = 16 * n_s + r;       // this thread's k column of the state
    // o-phase mapping: wave -> (t-tile, v-tile)
    const int i_o = wv >> 1;            // 0..3
    const int n_o = wv & 1;             // 0..1

    const float u_ = uin[h_idx * Kdim + lane];

    // ---- pre-loop: zero Am (upper triangle stays 0 forever), init h + Ht ----
    for (int i = tid; i < CL * LP; i += 512) Am[i] = 0;

    float h[4];
#pragma unroll
    for (int reg = 0; reg < 4; ++reg) {
        const int vloc = 16 * m_s + quad * 4 + reg;
        h[reg] = init[((size_t)bh * Kdim + k_) * Vdim + 32 * vh + vloc];
        Ht[vloc * LP + k_] = f2bf(h[reg]);
    }

    const int tv = tid >> 3;            // v-staging row (t)
    const int vl = (tid & 7) * 4;       // v-staging cols (v_local)

    // register prefetch of chunk 0
    float wl[8], ql[8], kl[8];
    float4_ vl4;
    {
        const size_t b0 = (size_t)bh * Tdim * Kdim;
#pragma unroll
        for (int tt = 0; tt < 8; ++tt) {
            const int t = 8 * wv + tt;
            wl[tt] = win[b0 + t * Kdim + lane];
            ql[tt] = rin[b0 + t * Kdim + lane];
            kl[tt] = kin[b0 + t * Kdim + lane];
        }
        vl4 = *(const float4_*)&vin[b0 + tv * Kdim + 32 * vh + vl];
    }

    // A-phase tile helper (i >= j lower-triangle tiles)
    auto atile = [&](int i, int j) {
        const int trow = 16 * i + r;
        short8 qa0 = *(const short8*)&Qh[trow * LP + quad * 8];
        short8 qa1 = *(const short8*)&Qh[trow * LP + 32 + quad * 8];
        const int srow = 16 * j + r;
        const int sb = (srow >> 3) & 7;
        short8 kb0 = *(const short8*)&Kh[srow * LP + ((quad ^ sb) << 3)];
        short8 kb1 = *(const short8*)&Kh[srow * LP + (((quad + 4) ^ sb) << 3)];
        float4_ acc = {0.f, 0.f, 0.f, 0.f};
        acc = MFMA(qa0, kb0, acc);
        acc = MFMA(qa1, kb1, acc);
#pragma unroll
        for (int reg = 0; reg < 4; ++reg) {
            const int tg = 16 * i + quad * 4 + reg;
            const float val = (tg > srow) ? acc[reg] : ((tg == srow) ? Dd[tg] : 0.f);
            Am[tg * LP + srow] = f2bf(val);
        }
    };

    for (int c = 0; c < NC; ++c) {
        const size_t base = ((size_t)bh * Tdim + (size_t)c * CL) * Kdim;

        // ---- pass 1: block-sums of w, V staging (from prefetched regs) ----
        float wreg[8];
        float cwl = 0.f;
#pragma unroll
        for (int tt = 0; tt < 8; ++tt) { wreg[tt] = wl[tt]; cwl += wl[tt]; }
        bsum[wv * 64 + lane] = cwl;
#pragma unroll
        for (int i = 0; i < 4; ++i) Vt[(vl + i) * LP + tv] = f2bf(vl4[i]);
        __syncthreads();                                        // B1: bsum/Vt ready

        // ---- pass 2: prefix sums, Qh/Kh/Qt/Dd ----
        float b[8];
#pragma unroll
        for (int j = 0; j < 8; ++j) b[j] = bsum[j * 64 + lane];
        float pref = 0.f;
#pragma unroll
        for (int j = 0; j < 8; ++j) if (j < wv) pref += b[j];
        const float Cmid = b[0] + b[1] + b[2] + b[3];            // cw_31
        const float eC = __expf(Cmid);
        float cwrun = pref;                                      // cw_{t-1} entering block
#pragma unroll
        for (int tt = 0; tt < 8; ++tt) {
            const int t = 8 * wv + tt;
            const float cwp = cwrun;                             // cw_{t-1}
            cwrun += wreg[tt];                                   // cw_t
            const float e1 = __expf(cwp - Cmid);
            Qh[t * LP + lane] = f2bf(ql[tt] * e1);
            Qt[t * LP + lane] = f2bf(ql[tt] * e1 * eC);          // q*e^{cw_{t-1}}
            const float e2 = __expf(Cmid - cwrun);
            Kh[t * LP + ((((lane >> 3) ^ ((t >> 3) & 7)) << 3) | (lane & 7))]
                = f2bf(kl[tt] * e2);
            float d3 = ql[tt] * u_ * kl[tt];
#pragma unroll
            for (int off = 32; off > 0; off >>= 1) d3 += __shfl_xor(d3, off);
            if (lane == 0) Dd[t] = d3;
        }
        // issue next-chunk loads now; they fly under the MFMA phases
        if (c + 1 < NC) {
            const size_t nb = base + (size_t)CL * Kdim;
#pragma unroll
            for (int tt = 0; tt < 8; ++tt) {
                const int t = 8 * wv + tt;
                wl[tt] = win[nb + t * Kdim + lane];
                ql[tt] = rin[nb + t * Kdim + lane];
                kl[tt] = kin[nb + t * Kdim + lane];
            }
            vl4 = *(const float4_*)&vin[nb + tv * Kdim + 32 * vh + vl];
        }
        __syncthreads();                                        // B2: Qh/Kh/Qt/Dd ready

        // ---- A-phase: 10 lower-triangle tiles over 8 waves ----
        {
            int i0, j0;
            if (wv == 0)      { i0 = 0; j0 = 0; }
            else if (wv < 3)  { i0 = 1; j0 = wv - 1; }
            else if (wv < 6)  { i0 = 2; j0 = wv - 3; }
            else              { i0 = 3; j0 = wv - 6; }
            atile(i0, j0);
            if (wv < 2) atile(3, 2 + wv);                        // tiles (3,2),(3,3)
        }
        __syncthreads();                                        // B3: Am ready

        // ---- o-phase: o = Am.V + Qt.h0  (wave -> t-tile i_o, v-tile n_o) ----
        {
            const int trow = 16 * i_o + r;
            short8 aa0 = *(const short8*)&Am[trow * LP + quad * 8];
            short8 aa1 = *(const short8*)&Am[trow * LP + 32 + quad * 8];
            short8 qt0 = *(const short8*)&Qt[trow * LP + quad * 8];
            short8 qt1 = *(const short8*)&Qt[trow * LP + 32 + quad * 8];
            const int vrow = 16 * n_o + r;
            short8 vb0 = *(const short8*)&Vt[vrow * LP + quad * 8];
            short8 vb1 = *(const short8*)&Vt[vrow * LP + 32 + quad * 8];
            short8 hb0 = *(const short8*)&Ht[vrow * LP + quad * 8];
            short8 hb1 = *(const short8*)&Ht[vrow * LP + 32 + quad * 8];
            float4_ o4 = {0.f, 0.f, 0.f, 0.f};
            o4 = MFMA(aa0, vb0, o4);
            o4 = MFMA(aa1, vb1, o4);
            o4 = MFMA(qt0, hb0, o4);
            o4 = MFMA(qt1, hb1, o4);
            float* op = oout + base;
#pragma unroll
            for (int reg = 0; reg < 4; ++reg)
                op[(16 * i_o + quad * 4 + reg) * Vdim + 32 * vh + 16 * n_o + r] = o4[reg];
        }

        // ---- S_c: D[v][k] = sum_s V[s][v] * Khat[s][k]  (wave -> m_s, n_s) ----
        float4_ sc = {0.f, 0.f, 0.f, 0.f};
        {
            const int vrow = 16 * m_s + r;
            short8 va0 = *(const short8*)&Vt[vrow * LP + quad * 8];
            short8 va1 = *(const short8*)&Vt[vrow * LP + 32 + quad * 8];
            short8 kc0, kc1;
            const int kb8 = k_ >> 3, k7 = k_ & 7;
#pragma unroll
            for (int j2 = 0; j2 < 8; ++j2) {
                const int s0 = quad * 8 + j2;
                kc0[j2] = Kh[s0 * LP + ((((kb8 ^ (s0 >> 3)) & 7) << 3) | k7)];
                const int s1 = 32 + s0;
                kc1[j2] = Kh[s1 * LP + ((((kb8 ^ (s1 >> 3)) & 7) << 3) | k7)];
            }
            sc = MFMA(va0, kc0, sc);
            sc = MFMA(va1, kc1, sc);
        }
        // per-k chunk totals (bsum is stable until next pass-1 write, after B4)
        float totk = 0.f, cmk = 0.f;
#pragma unroll
        for (int j = 0; j < 8; ++j) {
            const float bb = bsum[j * 64 + k_];
            totk += bb;
            if (j < 4) cmk += bb;
        }
        __syncthreads();                                        // B4: all LDS reads done

        // ---- state update + bf16 copy for next chunk's o-phase ----
        {
            const float eA = __expf(totk);                       // e^{cw_63}
            const float eS = __expf(totk - cmk);                 // Khat-acc -> Kbar-acc
#pragma unroll
            for (int reg = 0; reg < 4; ++reg) {
                h[reg] = h[reg] * eA + sc[reg] * eS;
                Ht[(16 * m_s + quad * 4 + reg) * LP + k_] = f2bf(h[reg]);
            }
        }
        // next iteration's B1 orders Ht writes before any wave's o-phase reads
    }

    // ---- final state ----
#pragma unroll
    for (int reg = 0; reg < 4; ++reg)
        fin[((size_t)bh * Kdim + k_) * Vdim + 32 * vh + 16 * m_s + quad * 4 + reg] = h[reg];
}

extern "C" void kernel_launch(void* const* d_in, const int* in_sizes, int n_in,
                              void* d_out, int out_size, void* d_ws, size_t ws_size,
                              hipStream_t stream) {
    const float* r    = (const float*)d_in[0];
    const float* k    = (const float*)d_in[1];
    const float* v    = (const float*)d_in[2];
    const float* w    = (const float*)d_in[3];
    const float* u    = (const float*)d_in[4];
    const float* init = (const float*)d_in[5];

    float* o   = (float*)d_out;
    float* fin = o + (size_t)Bdim * Hdim * Tdim * Vdim;

    (void)d_ws; (void)ws_size;
    rwkv6_fused<<<Bdim * Hdim * 2, 512, 0, stream>>>(r, k, v, w, u, init, o, fin);
}

// Round 3
// 303.466 us; speedup vs baseline: 1.3145x; 1.0259x over previous
//
#include <hip/hip_runtime.h>
#include <math.h>

// RWKV-6 fully-fused chunked scan.  B=4 H=32 T=2048 K=V=64.
// 256 blocks = (bh 0..127) x (v-half 0..1), 512 threads (8 waves), 1 block/CU.
// Round 3 changes vs the 154us fused version (counters: MfmaUtil 2.3%,
// VALUBusy 22%, HBM 17%, 7.6M LDS bank conflicts -> latency-bound):
//  1. Raw s_barrier + lgkmcnt(0) instead of __syncthreads(): __syncthreads
//     drains vmcnt(0) at every barrier, killing the next-chunk prefetch.
//     Now the 28 prefetch loads stay in flight across B2..B4 and are waited
//     (compiler-inserted vmcnt) only at next-chunk pass 1.
//  2. V staged by rows (thread owns one v-row, 4 consecutive s-cols) as one
//     packed ds_write_b64 with 16B-block XOR swizzle (blk ^= row>>3):
//     conflict-free writes AND b128 reads (was 4x u16 8-way scatter).
//  3. New transposed KhT[k][s] copy: pass-2 thread owns 8 consecutive
//     s-values of one k-column -> one ds_write_b128 (2-way);  S_c B-frag
//     becomes two conflict-free b128 reads (was 16x u16 ~4-way gather).
//  4. Ht gets the same block swizzle on both sides.
// Numerics identical to the verified kernel:
//   Qh = q*e^{cw_{t-1}-Cmid}, Kh = k*e^{Cmid-cw_s}  (Cmid = cw_31)
//   Qt = q*e^{cw_{t-1}};  A-diag = q*u*k;  S_c scaled by e^{tot-Cmid} per-k;
//   h = h*e^{tot} + S_c.

#define Bdim 4
#define Hdim 32
#define Tdim 2048
#define Kdim 64
#define Vdim 64
#define NC   32
#define CL   64
#define LP   72   // padded LDS row stride (bf16 elems): 144 B

typedef __attribute__((ext_vector_type(8))) short short8;
typedef __attribute__((ext_vector_type(4))) short short4_;
typedef __attribute__((ext_vector_type(4))) float float4_;

__device__ __forceinline__ short f2bf(float x) {
    unsigned u = __float_as_uint(x);
    unsigned r = (u + 0x7FFFu + ((u >> 16) & 1u)) >> 16;
    return (short)r;
}

#define MFMA(a, b, c) __builtin_amdgcn_mfma_f32_16x16x32_bf16(a, b, c, 0, 0, 0)

// Producer-visibility barrier WITHOUT the vmcnt(0) drain __syncthreads emits.
// lgkmcnt(0) makes this wave's ds_writes visible; s_barrier syncs the group;
// sched_barrier(0) pins compiler scheduling on both sides (no LDS op motion).
__device__ __forceinline__ void wg_barrier() {
    __builtin_amdgcn_sched_barrier(0);
    asm volatile("s_waitcnt lgkmcnt(0)");
    __builtin_amdgcn_s_barrier();
    __builtin_amdgcn_sched_barrier(0);
}

__global__ __launch_bounds__(512) void rwkv6_fused(
    const float* __restrict__ rin, const float* __restrict__ kin,
    const float* __restrict__ vin, const float* __restrict__ win,
    const float* __restrict__ uin, const float* __restrict__ init,
    float* __restrict__ oout, float* __restrict__ fin)
{
    __shared__ __attribute__((aligned(16))) short Qh[CL * LP];
    __shared__ __attribute__((aligned(16))) short Kh[CL * LP];   // row-major, block-swizzled
    __shared__ __attribute__((aligned(16))) short KhT[CL * LP];  // transposed [k][s], block-swizzled
    __shared__ __attribute__((aligned(16))) short Qt[CL * LP];
    __shared__ __attribute__((aligned(16))) short Am[CL * LP];
    __shared__ __attribute__((aligned(16))) short Vt[32 * LP];   // V^T[v_local][s], block-swizzled
    __shared__ __attribute__((aligned(16))) short Ht[32 * LP];   // h0^T[v_local][k], block-swizzled
    __shared__ float bsum[8 * 64];
    __shared__ float Dd[CL];

    const int tid  = threadIdx.x;
    const int wv   = tid >> 6;          // wave 0..7
    const int lane = tid & 63;          // k index in preprocessing
    const int quad = lane >> 4, r = lane & 15;

    const int bid = blockIdx.x;
    const int vh  = bid >> 7;           // v-half 0/1 (siblings share XCD: 128%8==0)
    const int bh  = bid & 127;
    const int h_idx = bh & (Hdim - 1);

    // state / S_c mapping: wave -> (v-tile m_s, k-tile n_s)
    const int m_s = wv >> 2;            // 0..1
    const int n_s = wv & 3;             // 0..3
    const int k_  = 16 * n_s + r;       // this thread's k column of the state
    // o-phase mapping: wave -> (t-tile, v-tile)
    const int i_o = wv >> 1;            // 0..3
    const int n_o = wv & 1;             // 0..1

    const float u_ = uin[h_idx * Kdim + lane];

    // V staging mapping: thread owns v-row (svrow), 4 consecutive s-cols
    const int svrow = tid & 31;         // v_local
    const int skq   = tid >> 5;         // 0..15 -> cols 4*skq .. 4*skq+3

    // 16B-block swizzled address helpers (logical [row][col], 8 blocks of 8 elems)
    auto blk_addr = [](const short* buf, int row, int blk) -> const char* {
        const int phys = blk ^ ((row >> 3) & 3);
        return (const char*)buf + row * 144 + phys * 16;
    };

    // ---- pre-loop: zero Am (upper triangle stays 0 forever), init h + Ht ----
    for (int i = tid; i < CL * LP; i += 512) Am[i] = 0;

    float h[4];
#pragma unroll
    for (int reg = 0; reg < 4; ++reg) {
        const int vloc = 16 * m_s + quad * 4 + reg;
        h[reg] = init[((size_t)bh * Kdim + k_) * Vdim + 32 * vh + vloc];
        const int hb = ((k_ >> 3) ^ ((vloc >> 3) & 3));
        *(short*)((char*)Ht + vloc * 144 + hb * 16 + (k_ & 7) * 2) = f2bf(h[reg]);
    }

    // register prefetch of chunk 0 (order: w, v first -- pass1 consumers)
    float wl[8], ql[8], kl[8], vls[4];
    {
        const size_t b0 = (size_t)bh * Tdim * Kdim;
#pragma unroll
        for (int tt = 0; tt < 8; ++tt) wl[tt] = win[b0 + (8 * wv + tt) * Kdim + lane];
#pragma unroll
        for (int i = 0; i < 4; ++i)
            vls[i] = vin[b0 + (4 * skq + i) * Kdim + 32 * vh + svrow];
#pragma unroll
        for (int tt = 0; tt < 8; ++tt) ql[tt] = rin[b0 + (8 * wv + tt) * Kdim + lane];
#pragma unroll
        for (int tt = 0; tt < 8; ++tt) kl[tt] = kin[b0 + (8 * wv + tt) * Kdim + lane];
    }

    // A-phase tile helper (i >= j lower-triangle tiles)
    auto atile = [&](int i, int j) {
        const int trow = 16 * i + r;
        short8 qa0 = *(const short8*)&Qh[trow * LP + quad * 8];
        short8 qa1 = *(const short8*)&Qh[trow * LP + 32 + quad * 8];
        const int srow = 16 * j + r;
        const int sb = (srow >> 3) & 7;
        short8 kb0 = *(const short8*)&Kh[srow * LP + ((quad ^ sb) << 3)];
        short8 kb1 = *(const short8*)&Kh[srow * LP + (((quad + 4) ^ sb) << 3)];
        float4_ acc = {0.f, 0.f, 0.f, 0.f};
        acc = MFMA(qa0, kb0, acc);
        acc = MFMA(qa1, kb1, acc);
#pragma unroll
        for (int reg = 0; reg < 4; ++reg) {
            const int tg = 16 * i + quad * 4 + reg;
            const float val = (tg > srow) ? acc[reg] : ((tg == srow) ? Dd[tg] : 0.f);
            Am[tg * LP + srow] = f2bf(val);
        }
    };

    for (int c = 0; c < NC; ++c) {
        const size_t base = ((size_t)bh * Tdim + (size_t)c * CL) * Kdim;

        // ---- pass 1: block-sums of w, V staging (packed b64, swizzled) ----
        float wreg[8];
        float cwl = 0.f;
#pragma unroll
        for (int tt = 0; tt < 8; ++tt) { wreg[tt] = wl[tt]; cwl += wl[tt]; }
        bsum[wv * 64 + lane] = cwl;
        {
            short4_ pack;
#pragma unroll
            for (int i = 0; i < 4; ++i) pack[i] = f2bf(vls[i]);
            const int vb = ((skq >> 1) ^ ((svrow >> 3) & 3));
            *(short4_*)((char*)Vt + svrow * 144 + vb * 16 + (skq & 1) * 8) = pack;
        }
        wg_barrier();                                           // B1: bsum/Vt ready

        // ---- pass 2: prefix sums, Qh/Kh/KhT/Qt/Dd ----
        float b[8];
#pragma unroll
        for (int j = 0; j < 8; ++j) b[j] = bsum[j * 64 + lane];
        float pref = 0.f;
#pragma unroll
        for (int j = 0; j < 8; ++j) if (j < wv) pref += b[j];
        const float Cmid = b[0] + b[1] + b[2] + b[3];            // cw_31
        const float eC = __expf(Cmid);
        float cwrun = pref;                                      // cw_{t-1} entering block
        short8 khrow;                                            // KhT[k=lane][8wv..8wv+7]
#pragma unroll
        for (int tt = 0; tt < 8; ++tt) {
            const int t = 8 * wv + tt;
            const float cwp = cwrun;                             // cw_{t-1}
            cwrun += wreg[tt];                                   // cw_t
            const float e1 = __expf(cwp - Cmid);
            Qh[t * LP + lane] = f2bf(ql[tt] * e1);
            Qt[t * LP + lane] = f2bf(ql[tt] * e1 * eC);          // q*e^{cw_{t-1}}
            const float e2 = __expf(Cmid - cwrun);
            const short kv = f2bf(kl[tt] * e2);
            Kh[t * LP + ((((lane >> 3) ^ ((t >> 3) & 7)) << 3) | (lane & 7))] = kv;
            khrow[tt] = kv;
            float d3 = ql[tt] * u_ * kl[tt];
#pragma unroll
            for (int off = 32; off > 0; off >>= 1) d3 += __shfl_xor(d3, off);
            if (lane == 0) Dd[t] = d3;
        }
        {   // packed transposed write: row k=lane, s-block = wv
            const int kb = (wv ^ ((lane >> 3) & 3));
            *(short8*)((char*)KhT + lane * 144 + kb * 16) = khrow;
        }
        // issue next-chunk loads; with raw barriers they stay in flight
        // across B2..B4 and are waited only at next pass 1 / pass 2 use.
        if (c + 1 < NC) {
            const size_t nb = base + (size_t)CL * Kdim;
#pragma unroll
            for (int tt = 0; tt < 8; ++tt) wl[tt] = win[nb + (8 * wv + tt) * Kdim + lane];
#pragma unroll
            for (int i = 0; i < 4; ++i)
                vls[i] = vin[nb + (4 * skq + i) * Kdim + 32 * vh + svrow];
#pragma unroll
            for (int tt = 0; tt < 8; ++tt) ql[tt] = rin[nb + (8 * wv + tt) * Kdim + lane];
#pragma unroll
            for (int tt = 0; tt < 8; ++tt) kl[tt] = kin[nb + (8 * wv + tt) * Kdim + lane];
        }
        wg_barrier();                                           // B2: Qh/Kh/KhT/Qt/Dd ready

        // ---- A-phase: 10 lower-triangle tiles over 8 waves ----
        {
            int i0, j0;
            if (wv == 0)      { i0 = 0; j0 = 0; }
            else if (wv < 3)  { i0 = 1; j0 = wv - 1; }
            else if (wv < 6)  { i0 = 2; j0 = wv - 3; }
            else              { i0 = 3; j0 = wv - 6; }
            atile(i0, j0);
            if (wv < 2) atile(3, 2 + wv);                        // tiles (3,2),(3,3)
        }
        wg_barrier();                                           // B3: Am ready

        // ---- o-phase: o = Am.V + Qt.h0  (wave -> t-tile i_o, v-tile n_o) ----
        {
            const int trow = 16 * i_o + r;
            short8 aa0 = *(const short8*)&Am[trow * LP + quad * 8];
            short8 aa1 = *(const short8*)&Am[trow * LP + 32 + quad * 8];
            short8 qt0 = *(const short8*)&Qt[trow * LP + quad * 8];
            short8 qt1 = *(const short8*)&Qt[trow * LP + 32 + quad * 8];
            const int vrow = 16 * n_o + r;
            short8 vb0 = *(const short8*)blk_addr(Vt, vrow, quad);
            short8 vb1 = *(const short8*)blk_addr(Vt, vrow, quad + 4);
            short8 hb0 = *(const short8*)blk_addr(Ht, vrow, quad);
            short8 hb1 = *(const short8*)blk_addr(Ht, vrow, quad + 4);
            float4_ o4 = {0.f, 0.f, 0.f, 0.f};
            o4 = MFMA(aa0, vb0, o4);
            o4 = MFMA(aa1, vb1, o4);
            o4 = MFMA(qt0, hb0, o4);
            o4 = MFMA(qt1, hb1, o4);
            float* op = oout + base;
#pragma unroll
            for (int reg = 0; reg < 4; ++reg)
                op[(16 * i_o + quad * 4 + reg) * Vdim + 32 * vh + 16 * n_o + r] = o4[reg];
        }

        // ---- S_c: D[m=v][n=k] = sum_s V[s][v]*Khat[s][k]  (wave -> m_s,n_s) ----
        float4_ sc = {0.f, 0.f, 0.f, 0.f};
        {
            const int vrow = 16 * m_s + r;
            short8 va0 = *(const short8*)blk_addr(Vt, vrow, quad);
            short8 va1 = *(const short8*)blk_addr(Vt, vrow, quad + 4);
            short8 kc0 = *(const short8*)blk_addr(KhT, k_, quad);
            short8 kc1 = *(const short8*)blk_addr(KhT, k_, quad + 4);
            sc = MFMA(va0, kc0, sc);
            sc = MFMA(va1, kc1, sc);
        }
        // per-k chunk totals (bsum stable until next pass-1 write, after B4)
        float totk = 0.f, cmk = 0.f;
#pragma unroll
        for (int j = 0; j < 8; ++j) {
            const float bb = bsum[j * 64 + k_];
            totk += bb;
            if (j < 4) cmk += bb;
        }
        wg_barrier();                                           // B4: all LDS reads done

        // ---- state update + swizzled bf16 copy for next chunk's o-phase ----
        {
            const float eA = __expf(totk);                       // e^{cw_63}
            const float eS = __expf(totk - cmk);                 // Khat-acc -> Kbar-acc
#pragma unroll
            for (int reg = 0; reg < 4; ++reg) {
                h[reg] = h[reg] * eA + sc[reg] * eS;
                const int vloc = 16 * m_s + quad * 4 + reg;
                const int hb = ((k_ >> 3) ^ ((vloc >> 3) & 3));
                *(short*)((char*)Ht + vloc * 144 + hb * 16 + (k_ & 7) * 2) = f2bf(h[reg]);
            }
        }
        // next iteration's B1 orders Ht writes before any wave's o-phase reads
    }

    // ---- final state ----
#pragma unroll
    for (int reg = 0; reg < 4; ++reg)
        fin[((size_t)bh * Kdim + k_) * Vdim + 32 * vh + 16 * m_s + quad * 4 + reg] = h[reg];
}

extern "C" void kernel_launch(void* const* d_in, const int* in_sizes, int n_in,
                              void* d_out, int out_size, void* d_ws, size_t ws_size,
                              hipStream_t stream) {
    const float* r    = (const float*)d_in[0];
    const float* k    = (const float*)d_in[1];
    const float* v    = (const float*)d_in[2];
    const float* w    = (const float*)d_in[3];
    const float* u    = (const float*)d_in[4];
    const float* init = (const float*)d_in[5];

    float* o   = (float*)d_out;
    float* fin = o + (size_t)Bdim * Hdim * Tdim * Vdim;

    (void)d_ws; (void)ws_size;
    rwkv6_fused<<<Bdim * Hdim * 2, 512, 0, stream>>>(r, k, v, w, u, init, o, fin);
}